// Round 1
// baseline (672.731 us; speedup 1.0000x reference)
//
#include <hip/hip_runtime.h>
#include <hip/hip_bf16.h>
#include <stdint.h>

#define NN 50000
#define NE 800000
#define IND 128
#define HID 256
#define MPAD 50048      // 391 * 128
#define NTILES_M 391

typedef unsigned int uint32;
typedef unsigned short ushort_t;
typedef __attribute__((ext_vector_type(8))) short short8;
typedef __attribute__((ext_vector_type(4))) float f32x4;

typedef const __attribute__((address_space(1))) void* gptr_t;
typedef __attribute__((address_space(3))) void* lptr_t;

__device__ __forceinline__ ushort_t f2b(float f) {
  uint32 u = __float_as_uint(f);
  u = (u + 0x7fffu + ((u >> 16) & 1u)) >> 16;
  return (ushort_t)u;
}
__device__ __forceinline__ float blo(uint32 u) { return __uint_as_float(u << 16); }
__device__ __forceinline__ float bhi(uint32 u) { return __uint_as_float(u & 0xffff0000u); }
__device__ __forceinline__ uint32 pack2(float a, float b) {
  return (uint32)f2b(a) | ((uint32)f2b(b) << 16);
}

// ---------------- CSR build ----------------
__global__ void zero_k(int* __restrict__ p, int n) {
  int i = blockIdx.x * 256 + threadIdx.x;
  if (i < n) p[i] = 0;
}

__global__ void hist_k(const int* __restrict__ dst, int* __restrict__ cnt) {
  int e = blockIdx.x * 256 + threadIdx.x;
  if (e < NE) atomicAdd(&cnt[dst[e]], 1);
}

// single-block exclusive scan over cnt (in `cur`): writes rp[] and resets cur[] to
// the exclusive offsets (used as scatter cursors).
__global__ void scan_k(int* __restrict__ cur, int* __restrict__ rp) {
  __shared__ int wsum[16];
  __shared__ int sbase;
  const int tid = threadIdx.x;
  const int ln = tid & 63, wv = tid >> 6;
  if (tid == 0) sbase = 0;
  __syncthreads();
  for (int off = 0; off < NN; off += 1024) {
    int i = off + tid;
    int v = (i < NN) ? cur[i] : 0;
    int x = v;
#pragma unroll
    for (int d = 1; d < 64; d <<= 1) {
      int t = __shfl_up(x, d, 64);
      if (ln >= d) x += t;
    }
    if (ln == 63) wsum[wv] = x;
    __syncthreads();
    if (tid < 16) {
      int s = wsum[tid];
#pragma unroll
      for (int d = 1; d < 16; d <<= 1) {
        int t = __shfl_up(s, d, 64);
        if (tid >= d) s += t;
      }
      wsum[tid] = s;
    }
    __syncthreads();
    int base = sbase;
    int incl = x + (wv ? wsum[wv - 1] : 0) + base;
    __syncthreads();
    if (tid == 1023) sbase = incl;
    if (i < NN) { int excl = incl - v; rp[i] = excl; cur[i] = excl; }
    __syncthreads();
  }
  if (tid == 0) rp[NN] = NE;
}

__global__ void scatter_k(const int* __restrict__ src, const int* __restrict__ dst,
                          int* __restrict__ cur, int* __restrict__ esrc) {
  int e = blockIdx.x * 256 + threadIdx.x;
  if (e < NE) {
    int p = atomicAdd(&cur[dst[e]], 1);
    esrc[p] = src[e];
  }
}

// ---------------- weight / BN prep ----------------
// wT[n][k] = (bf16) w[k][n];  w is K x 256 row-major
__global__ void prepw_k(const float* __restrict__ w, ushort_t* __restrict__ wt, int K) {
  int n = blockIdx.x, k = threadIdx.x;
  if (k < K) wt[n * K + k] = f2b(w[(size_t)k * HID + n]);
}

__global__ void prepbn_k(const float* b1_0, const float* b2_0, const float* g0,
                         const float* be0, const float* m0, const float* v0,
                         const float* b1_r, const float* b2_r, const float* g_r,
                         const float* be_r, const float* m_r, const float* v_r,
                         float* sc1, float* bi1, float* sc2, float* bi2) {
  int l = blockIdx.x, j = threadIdx.x;
  float b1, b2, g, be, m, v;
  if (l == 0) { b1 = b1_0[j]; b2 = b2_0[j]; g = g0[j]; be = be0[j]; m = m0[j]; v = v0[j]; }
  else { int o = (l - 1) * HID + j; b1 = b1_r[o]; b2 = b2_r[o]; g = g_r[o]; be = be_r[o]; m = m_r[o]; v = v_r[o]; }
  int o = l * HID + j;
  sc1[o] = 1.0f;
  bi1[o] = b1;
  float s = g * rsqrtf(v + 1e-5f);
  sc2[o] = s;
  bi2[o] = (b2 - m) * s + be;
}

// ---------------- aggregation: z = h + sum_{j in N(i)} h_j ----------------
// layer 0: fp32 input x (NN x 128) -> bf16 z (MPAD x 128). wave per node, lane holds 2 dims.
__global__ void agg_f32_k(const float* __restrict__ x, const int* __restrict__ rp,
                          const int* __restrict__ esrc, ushort_t* __restrict__ z) {
  int wid = threadIdx.x >> 6, lane = threadIdx.x & 63;
  int node = blockIdx.x * 4 + wid;
  if (node >= NN) return;
  const float2* xp = (const float2*)x;
  float2 a = xp[(size_t)node * 64 + lane];
  int e0 = rp[node], e1 = rp[node + 1];
  for (int e = e0; e < e1; e++) {
    int s = esrc[e];
    float2 u = xp[(size_t)s * 64 + lane];
    a.x += u.x; a.y += u.y;
  }
  ((uint32*)z)[(size_t)node * 64 + lane] = pack2(a.x, a.y);
}

// layers 1..2: bf16 input h (MPAD x 256) -> bf16 z. wave per node, lane holds 4 dims.
__global__ void agg_bf_k(const ushort_t* __restrict__ h, const int* __restrict__ rp,
                         const int* __restrict__ esrc, ushort_t* __restrict__ z) {
  int wid = threadIdx.x >> 6, lane = threadIdx.x & 63;
  int node = blockIdx.x * 4 + wid;
  if (node >= NN) return;
  const uint2* hp = (const uint2*)h;
  uint2 v = hp[(size_t)node * 64 + lane];
  float a0 = blo(v.x), a1 = bhi(v.x), a2 = blo(v.y), a3 = bhi(v.y);
  int e0 = rp[node], e1 = rp[node + 1];
  for (int e = e0; e < e1; e++) {
    int s = esrc[e];
    uint2 u = hp[(size_t)s * 64 + lane];
    a0 += blo(u.x); a1 += bhi(u.x); a2 += blo(u.y); a3 += bhi(u.y);
  }
  uint2 o; o.x = pack2(a0, a1); o.y = pack2(a2, a3);
  ((uint2*)z)[(size_t)node * 64 + lane] = o;
}

// ---------------- GEMM: C[m][n] = sum_k A[m][k] * Bt[n][k], + per-col scale/bias ----------------
// A: MPAD x K bf16 row-major; Bt: 256 x K bf16 row-major. 128x128 tile, BK=32,
// 4 waves each computing 64x64 via 4x4 of mfma_f32_16x16x32_bf16.
__global__ __launch_bounds__(256) void gemm_k(
    const ushort_t* __restrict__ A, const ushort_t* __restrict__ Bt,
    const float* __restrict__ sc, const float* __restrict__ bi,
    void* __restrict__ out, int K, int lrelu, int f32out) {
  __shared__ ushort_t As[128 * 32];
  __shared__ ushort_t Bs[128 * 32];
  const int tid = threadIdx.x;
  const int lane = tid & 63;
  const int wid = tid >> 6;
  const int m0 = blockIdx.x * 128;
  const int n0 = blockIdx.y * 128;
  const int wm = (wid & 1) * 64;
  const int wn = (wid >> 1) * 64;
  const int srow = tid >> 2;          // 0..63
  const int sch = (tid & 3) * 8;      // bf16 offset in 32-wide row
  const int fr = lane & 15;
  const int fk = (lane >> 4) * 8;

  f32x4 zero = {0.f, 0.f, 0.f, 0.f};
  f32x4 acc[4][4];
#pragma unroll
  for (int i = 0; i < 4; i++)
#pragma unroll
    for (int j = 0; j < 4; j++) acc[i][j] = zero;

  for (int kk = 0; kk < K; kk += 32) {
    const ushort_t* ga = A + (size_t)(m0 + srow) * K + kk + sch;
    const ushort_t* gb = Bt + (size_t)(n0 + srow) * K + kk + sch;
    ushort_t* la = As + srow * 32 + sch;
    ushort_t* lb = Bs + srow * 32 + sch;
    __builtin_amdgcn_global_load_lds((gptr_t)ga, (lptr_t)la, 16, 0, 0);
    __builtin_amdgcn_global_load_lds((gptr_t)(ga + (size_t)64 * K), (lptr_t)(la + 64 * 32), 16, 0, 0);
    __builtin_amdgcn_global_load_lds((gptr_t)gb, (lptr_t)lb, 16, 0, 0);
    __builtin_amdgcn_global_load_lds((gptr_t)(gb + (size_t)64 * K), (lptr_t)(lb + 64 * 32), 16, 0, 0);
    __syncthreads();

    short8 af[4], bfv[4];
#pragma unroll
    for (int i = 0; i < 4; i++)
      af[i] = *(const short8*)(As + (wm + i * 16 + fr) * 32 + fk);
#pragma unroll
    for (int j = 0; j < 4; j++)
      bfv[j] = *(const short8*)(Bs + (wn + j * 16 + fr) * 32 + fk);
#pragma unroll
    for (int i = 0; i < 4; i++)
#pragma unroll
      for (int j = 0; j < 4; j++)
        acc[i][j] = __builtin_amdgcn_mfma_f32_16x16x32_bf16(af[i], bfv[j], acc[i][j], 0, 0, 0);
    __syncthreads();
  }

  const int er = lane >> 4;   // C/D: row = er*4 + r, col = ec  (m89-verified)
  const int ec = lane & 15;
#pragma unroll
  for (int j = 0; j < 4; j++) {
    int col = n0 + wn + j * 16 + ec;
    float s = sc[col], b = bi[col];
#pragma unroll
    for (int i = 0; i < 4; i++) {
      int row0 = m0 + wm + i * 16 + er * 4;
#pragma unroll
      for (int r = 0; r < 4; r++) {
        float v = acc[i][j][r] * s + b;
        if (lrelu) v = (v > 0.f) ? v : 0.01f * v;
        int row = row0 + r;
        if (f32out) {
          if (row < NN) ((float*)out)[(size_t)row * HID + col] = v;
        } else {
          ((ushort_t*)out)[(size_t)row * HID + col] = f2b(v);
        }
      }
    }
  }
}

extern "C" void kernel_launch(void* const* d_in, const int* in_sizes, int n_in,
                              void* d_out, int out_size, void* d_ws, size_t ws_size,
                              hipStream_t stream) {
  const float* x    = (const float*)d_in[0];
  const int*   src  = (const int*)d_in[1];
  const int*   dst  = (const int*)d_in[2];
  const float* w1_0 = (const float*)d_in[3];
  const float* b1_0 = (const float*)d_in[4];
  const float* w2_0 = (const float*)d_in[5];
  const float* b2_0 = (const float*)d_in[6];
  const float* g0   = (const float*)d_in[7];
  const float* be0  = (const float*)d_in[8];
  const float* m0   = (const float*)d_in[9];
  const float* v0   = (const float*)d_in[10];
  const float* w1_r = (const float*)d_in[11];
  const float* b1_r = (const float*)d_in[12];
  const float* w2_r = (const float*)d_in[13];
  const float* b2_r = (const float*)d_in[14];
  const float* g_r  = (const float*)d_in[15];
  const float* be_r = (const float*)d_in[16];
  const float* m_r  = (const float*)d_in[17];
  const float* v_r  = (const float*)d_in[18];

  char* ws = (char*)d_ws;
  size_t off = 0;
  auto alloc = [&](size_t bytes) {
    void* p = ws + off;
    off = (off + bytes + 255) & ~(size_t)255;
    return p;
  };
  ushort_t* bufA  = (ushort_t*)alloc((size_t)MPAD * HID * 2);
  ushort_t* bufB  = (ushort_t*)alloc((size_t)MPAD * HID * 2);
  int*      rp    = (int*)alloc((NN + 1) * sizeof(int));
  int*      cur   = (int*)alloc(NN * sizeof(int));
  int*      esrc  = (int*)alloc((size_t)NE * sizeof(int));
  ushort_t* w1_0t = (ushort_t*)alloc((size_t)HID * IND * 2);
  ushort_t* w2_0t = (ushort_t*)alloc((size_t)HID * HID * 2);
  ushort_t* w1r0t = (ushort_t*)alloc((size_t)HID * HID * 2);
  ushort_t* w2r0t = (ushort_t*)alloc((size_t)HID * HID * 2);
  ushort_t* w1r1t = (ushort_t*)alloc((size_t)HID * HID * 2);
  ushort_t* w2r1t = (ushort_t*)alloc((size_t)HID * HID * 2);
  float*    sc1   = (float*)alloc(3 * HID * sizeof(float));
  float*    bi1   = (float*)alloc(3 * HID * sizeof(float));
  float*    sc2   = (float*)alloc(3 * HID * sizeof(float));
  float*    bi2   = (float*)alloc(3 * HID * sizeof(float));
  (void)ws_size; (void)in_sizes; (void)n_in; (void)out_size;

  // CSR build
  zero_k<<<(NN + 255) / 256, 256, 0, stream>>>(cur, NN);
  hist_k<<<(NE + 255) / 256, 256, 0, stream>>>(dst, cur);
  scan_k<<<1, 1024, 0, stream>>>(cur, rp);
  scatter_k<<<(NE + 255) / 256, 256, 0, stream>>>(src, dst, cur, esrc);

  // weight/BN prep
  prepw_k<<<HID, 256, 0, stream>>>(w1_0, w1_0t, IND);
  prepw_k<<<HID, 256, 0, stream>>>(w2_0, w2_0t, HID);
  prepw_k<<<HID, 256, 0, stream>>>(w1_r, w1r0t, HID);
  prepw_k<<<HID, 256, 0, stream>>>(w1_r + (size_t)HID * HID, w1r1t, HID);
  prepw_k<<<HID, 256, 0, stream>>>(w2_r, w2r0t, HID);
  prepw_k<<<HID, 256, 0, stream>>>(w2_r + (size_t)HID * HID, w2r1t, HID);
  prepbn_k<<<3, 256, 0, stream>>>(b1_0, b2_0, g0, be0, m0, v0,
                                  b1_r, b2_r, g_r, be_r, m_r, v_r,
                                  sc1, bi1, sc2, bi2);

  dim3 gg(NTILES_M, 2);
  // layer 0
  agg_f32_k<<<NN / 4, 256, 0, stream>>>(x, rp, esrc, bufA);
  gemm_k<<<gg, 256, 0, stream>>>(bufA, w1_0t, sc1, bi1, bufB, IND, 1, 0);
  gemm_k<<<gg, 256, 0, stream>>>(bufB, w2_0t, sc2, bi2, bufA, HID, 1, 0);
  // layer 1
  agg_bf_k<<<NN / 4, 256, 0, stream>>>(bufA, rp, esrc, bufB);
  gemm_k<<<gg, 256, 0, stream>>>(bufB, w1r0t, sc1 + HID, bi1 + HID, bufA, HID, 1, 0);
  gemm_k<<<gg, 256, 0, stream>>>(bufA, w2r0t, sc2 + HID, bi2 + HID, bufB, HID, 1, 0);
  // layer 2
  agg_bf_k<<<NN / 4, 256, 0, stream>>>(bufB, rp, esrc, bufA);
  gemm_k<<<gg, 256, 0, stream>>>(bufA, w1r1t, sc1 + 2 * HID, bi1 + 2 * HID, bufB, HID, 1, 0);
  gemm_k<<<gg, 256, 0, stream>>>(bufB, w2r1t, sc2 + 2 * HID, bi2 + 2 * HID, d_out, HID, 0, 1);
}

// Round 2
// 538.957 us; speedup vs baseline: 1.2482x; 1.2482x over previous
//
#include <hip/hip_runtime.h>
#include <hip/hip_bf16.h>
#include <stdint.h>

#define NN 50000
#define NE 800000
#define IND 128
#define HID 256
#define MPAD 50048      // 391 * 128
#define NTILES_M 391
#define NBLK 49         // ceil(NN/1024)

typedef unsigned int uint32;
typedef unsigned short ushort_t;
typedef __attribute__((ext_vector_type(8))) short short8;
typedef __attribute__((ext_vector_type(4))) float f32x4;

typedef const __attribute__((address_space(1))) void* gptr_t;
typedef __attribute__((address_space(3))) void* lptr_t;

__device__ __forceinline__ ushort_t f2b(float f) {
  uint32 u = __float_as_uint(f);
  u = (u + 0x7fffu + ((u >> 16) & 1u)) >> 16;
  return (ushort_t)u;
}
__device__ __forceinline__ float blo(uint32 u) { return __uint_as_float(u << 16); }
__device__ __forceinline__ float bhi(uint32 u) { return __uint_as_float(u & 0xffff0000u); }
__device__ __forceinline__ uint32 pack2(float a, float b) {
  return (uint32)f2b(a) | ((uint32)f2b(b) << 16);
}

// ---------------- CSR build ----------------
__global__ void zero_k(int* __restrict__ p, int n) {
  int i = blockIdx.x * 256 + threadIdx.x;
  if (i < n) p[i] = 0;
}

__global__ void hist_k(const int* __restrict__ dst, int* __restrict__ cnt) {
  int e = blockIdx.x * 256 + threadIdx.x;
  if (e < NE) atomicAdd(&cnt[dst[e]], 1);
}

// hierarchical scan, phase 1: per-1024-block sums
__global__ void bsum_k(const int* __restrict__ cnt, int* __restrict__ bsum) {
  __shared__ int ws[16];
  const int tid = threadIdx.x, ln = tid & 63, wv = tid >> 6;
  int i = blockIdx.x * 1024 + tid;
  int v = (i < NN) ? cnt[i] : 0;
#pragma unroll
  for (int d = 32; d; d >>= 1) v += __shfl_down(v, d, 64);
  if (ln == 0) ws[wv] = v;
  __syncthreads();
  if (tid < 16) {
    int s = ws[tid];
#pragma unroll
    for (int d = 8; d; d >>= 1) s += __shfl_down(s, d, 64);
    if (tid == 0) bsum[blockIdx.x] = s;
  }
}

// phase 2: single-wave exclusive scan of the 49 block sums; also writes rp[NN]
__global__ void bscan_k(int* __restrict__ bsum, int* __restrict__ rp) {
  int tid = threadIdx.x;
  int v = (tid < NBLK) ? bsum[tid] : 0;
  int x = v;
#pragma unroll
  for (int d = 1; d < 64; d <<= 1) {
    int t = __shfl_up(x, d, 64);
    if (tid >= d) x += t;
  }
  if (tid < NBLK) bsum[tid] = x - v;
  if (tid == 0) rp[NN] = NE;
}

// phase 3: per-block exclusive scan + block offset -> rp, cur
__global__ void scan2_k(const int* __restrict__ cnt, const int* __restrict__ bsum,
                        int* __restrict__ rp, int* __restrict__ cur) {
  __shared__ int ws[16];
  const int tid = threadIdx.x, ln = tid & 63, wv = tid >> 6;
  int i = blockIdx.x * 1024 + tid;
  int v = (i < NN) ? cnt[i] : 0;
  int x = v;
#pragma unroll
  for (int d = 1; d < 64; d <<= 1) {
    int t = __shfl_up(x, d, 64);
    if (ln >= d) x += t;
  }
  if (ln == 63) ws[wv] = x;
  __syncthreads();
  if (tid < 16) {
    int s = ws[tid];
#pragma unroll
    for (int d = 1; d < 16; d <<= 1) {
      int t = __shfl_up(s, d, 64);
      if (tid >= d) s += t;
    }
    ws[tid] = s;
  }
  __syncthreads();
  int excl = x - v + (wv ? ws[wv - 1] : 0) + bsum[blockIdx.x];
  if (i < NN) { rp[i] = excl; cur[i] = excl; }
}

__global__ void scatter_k(const int* __restrict__ src, const int* __restrict__ dst,
                          int* __restrict__ cur, int* __restrict__ esrc) {
  int e = blockIdx.x * 256 + threadIdx.x;
  if (e < NE) {
    int p = atomicAdd(&cur[dst[e]], 1);
    esrc[p] = src[e];
  }
}

// ---------------- weight / BN prep ----------------
// wt layout: w1_0t(HID*IND), w2_0t, w1r0t, w2r0t, w1r1t, w2r1t (each HID*HID)
__global__ void prepw_k(const float* __restrict__ w1_0, const float* __restrict__ w2_0,
                        const float* __restrict__ w1_r, const float* __restrict__ w2_r,
                        ushort_t* __restrict__ wt) {
  const int which = blockIdx.y;
  const int n = blockIdx.x, k = threadIdx.x;
  const float* w; ushort_t* o; int K = HID;
  switch (which) {
    case 0: w = w1_0; o = wt; K = IND; break;
    case 1: w = w2_0; o = wt + HID * IND; break;
    case 2: w = w1_r; o = wt + HID * IND + 1 * HID * HID; break;
    case 3: w = w2_r; o = wt + HID * IND + 2 * HID * HID; break;
    case 4: w = w1_r + HID * HID; o = wt + HID * IND + 3 * HID * HID; break;
    default: w = w2_r + HID * HID; o = wt + HID * IND + 4 * HID * HID; break;
  }
  if (k < K) o[n * K + k] = f2b(w[(size_t)k * HID + n]);
}

__global__ void prepbn_k(const float* b1_0, const float* b2_0, const float* g0,
                         const float* be0, const float* m0, const float* v0,
                         const float* b1_r, const float* b2_r, const float* g_r,
                         const float* be_r, const float* m_r, const float* v_r,
                         float* sc1, float* bi1, float* sc2, float* bi2) {
  int l = blockIdx.x, j = threadIdx.x;
  float b1, b2, g, be, m, v;
  if (l == 0) { b1 = b1_0[j]; b2 = b2_0[j]; g = g0[j]; be = be0[j]; m = m0[j]; v = v0[j]; }
  else { int o = (l - 1) * HID + j; b1 = b1_r[o]; b2 = b2_r[o]; g = g_r[o]; be = be_r[o]; m = m_r[o]; v = v_r[o]; }
  int o = l * HID + j;
  sc1[o] = 1.0f;
  bi1[o] = b1;
  float s = g * rsqrtf(v + 1e-5f);
  sc2[o] = s;
  bi2[o] = (b2 - m) * s + be;
}

// ---------------- aggregation: z = h + sum_{j in N(i)} h_j ----------------
// layer 0: fp32 input x (NN x 128) -> bf16 z. wave/node, lane holds 2 dims, 8-edge MLP unroll.
__global__ void agg_f32_k(const float* __restrict__ x, const int* __restrict__ rp,
                          const int* __restrict__ esrc, ushort_t* __restrict__ z) {
  int wid = threadIdx.x >> 6, lane = threadIdx.x & 63;
  int node = blockIdx.x * 4 + wid;
  if (node >= NN) return;
  const float2* xp = (const float2*)x;
  float2 a = xp[(size_t)node * 64 + lane];
  int e0 = rp[node], e1 = rp[node + 1];
  int e = e0;
  for (; e + 8 <= e1; e += 8) {
    int s[8];
#pragma unroll
    for (int q = 0; q < 8; q++) s[q] = esrc[e + q];
    float2 u[8];
#pragma unroll
    for (int q = 0; q < 8; q++) u[q] = xp[(size_t)s[q] * 64 + lane];
#pragma unroll
    for (int q = 0; q < 8; q++) { a.x += u[q].x; a.y += u[q].y; }
  }
  for (; e < e1; e++) {
    int s = esrc[e];
    float2 u = xp[(size_t)s * 64 + lane];
    a.x += u.x; a.y += u.y;
  }
  ((uint32*)z)[(size_t)node * 64 + lane] = pack2(a.x, a.y);
}

// layers 1..2: bf16 h (MPAD x 256) -> bf16 z. wave/node, lane holds 4 dims, 8-edge MLP unroll.
__global__ void agg_bf_k(const ushort_t* __restrict__ h, const int* __restrict__ rp,
                         const int* __restrict__ esrc, ushort_t* __restrict__ z) {
  int wid = threadIdx.x >> 6, lane = threadIdx.x & 63;
  int node = blockIdx.x * 4 + wid;
  if (node >= NN) return;
  const uint2* hp = (const uint2*)h;
  uint2 v = hp[(size_t)node * 64 + lane];
  float a0 = blo(v.x), a1 = bhi(v.x), a2 = blo(v.y), a3 = bhi(v.y);
  int e0 = rp[node], e1 = rp[node + 1];
  int e = e0;
  for (; e + 8 <= e1; e += 8) {
    int s[8];
#pragma unroll
    for (int q = 0; q < 8; q++) s[q] = esrc[e + q];
    uint2 u[8];
#pragma unroll
    for (int q = 0; q < 8; q++) u[q] = hp[(size_t)s[q] * 64 + lane];
#pragma unroll
    for (int q = 0; q < 8; q++) {
      a0 += blo(u[q].x); a1 += bhi(u[q].x); a2 += blo(u[q].y); a3 += bhi(u[q].y);
    }
  }
  for (; e < e1; e++) {
    int s = esrc[e];
    uint2 u = hp[(size_t)s * 64 + lane];
    a0 += blo(u.x); a1 += bhi(u.x); a2 += blo(u.y); a3 += bhi(u.y);
  }
  uint2 o; o.x = pack2(a0, a1); o.y = pack2(a2, a3);
  ((uint2*)z)[(size_t)node * 64 + lane] = o;
}

// ---------------- GEMM: C[m][n] = sum_k A[m][k] * Bt[n][k], + per-col scale/bias ----------------
__global__ __launch_bounds__(256) void gemm_k(
    const ushort_t* __restrict__ A, const ushort_t* __restrict__ Bt,
    const float* __restrict__ sc, const float* __restrict__ bi,
    void* __restrict__ out, int K, int lrelu, int f32out) {
  __shared__ ushort_t As[128 * 32];
  __shared__ ushort_t Bs[128 * 32];
  const int tid = threadIdx.x;
  const int lane = tid & 63;
  const int wid = tid >> 6;
  const int m0 = blockIdx.x * 128;
  const int n0 = blockIdx.y * 128;
  const int wm = (wid & 1) * 64;
  const int wn = (wid >> 1) * 64;
  const int srow = tid >> 2;
  const int sch = (tid & 3) * 8;
  const int fr = lane & 15;
  const int fk = (lane >> 4) * 8;

  f32x4 zero = {0.f, 0.f, 0.f, 0.f};
  f32x4 acc[4][4];
#pragma unroll
  for (int i = 0; i < 4; i++)
#pragma unroll
    for (int j = 0; j < 4; j++) acc[i][j] = zero;

  for (int kk = 0; kk < K; kk += 32) {
    const ushort_t* ga = A + (size_t)(m0 + srow) * K + kk + sch;
    const ushort_t* gb = Bt + (size_t)(n0 + srow) * K + kk + sch;
    ushort_t* la = As + srow * 32 + sch;
    ushort_t* lb = Bs + srow * 32 + sch;
    __builtin_amdgcn_global_load_lds((gptr_t)ga, (lptr_t)la, 16, 0, 0);
    __builtin_amdgcn_global_load_lds((gptr_t)(ga + (size_t)64 * K), (lptr_t)(la + 64 * 32), 16, 0, 0);
    __builtin_amdgcn_global_load_lds((gptr_t)gb, (lptr_t)lb, 16, 0, 0);
    __builtin_amdgcn_global_load_lds((gptr_t)(gb + (size_t)64 * K), (lptr_t)(lb + 64 * 32), 16, 0, 0);
    __syncthreads();

    short8 af[4], bfv[4];
#pragma unroll
    for (int i = 0; i < 4; i++)
      af[i] = *(const short8*)(As + (wm + i * 16 + fr) * 32 + fk);
#pragma unroll
    for (int j = 0; j < 4; j++)
      bfv[j] = *(const short8*)(Bs + (wn + j * 16 + fr) * 32 + fk);
#pragma unroll
    for (int i = 0; i < 4; i++)
#pragma unroll
      for (int j = 0; j < 4; j++)
        acc[i][j] = __builtin_amdgcn_mfma_f32_16x16x32_bf16(af[i], bfv[j], acc[i][j], 0, 0, 0);
    __syncthreads();
  }

  const int er = lane >> 4;
  const int ec = lane & 15;
#pragma unroll
  for (int j = 0; j < 4; j++) {
    int col = n0 + wn + j * 16 + ec;
    float s = sc[col], b = bi[col];
#pragma unroll
    for (int i = 0; i < 4; i++) {
      int row0 = m0 + wm + i * 16 + er * 4;
#pragma unroll
      for (int r = 0; r < 4; r++) {
        float v = acc[i][j][r] * s + b;
        if (lrelu) v = (v > 0.f) ? v : 0.01f * v;
        int row = row0 + r;
        if (f32out) {
          if (row < NN) ((float*)out)[(size_t)row * HID + col] = v;
        } else {
          ((ushort_t*)out)[(size_t)row * HID + col] = f2b(v);
        }
      }
    }
  }
}

extern "C" void kernel_launch(void* const* d_in, const int* in_sizes, int n_in,
                              void* d_out, int out_size, void* d_ws, size_t ws_size,
                              hipStream_t stream) {
  const float* x    = (const float*)d_in[0];
  const int*   src  = (const int*)d_in[1];
  const int*   dst  = (const int*)d_in[2];
  const float* w1_0 = (const float*)d_in[3];
  const float* b1_0 = (const float*)d_in[4];
  const float* w2_0 = (const float*)d_in[5];
  const float* b2_0 = (const float*)d_in[6];
  const float* g0   = (const float*)d_in[7];
  const float* be0  = (const float*)d_in[8];
  const float* m0   = (const float*)d_in[9];
  const float* v0   = (const float*)d_in[10];
  const float* w1_r = (const float*)d_in[11];
  const float* b1_r = (const float*)d_in[12];
  const float* w2_r = (const float*)d_in[13];
  const float* b2_r = (const float*)d_in[14];
  const float* g_r  = (const float*)d_in[15];
  const float* be_r = (const float*)d_in[16];
  const float* m_r  = (const float*)d_in[17];
  const float* v_r  = (const float*)d_in[18];

  char* ws = (char*)d_ws;
  size_t off = 0;
  auto alloc = [&](size_t bytes) {
    void* p = ws + off;
    off = (off + bytes + 255) & ~(size_t)255;
    return p;
  };
  ushort_t* bufA  = (ushort_t*)alloc((size_t)MPAD * HID * 2);
  ushort_t* bufB  = (ushort_t*)alloc((size_t)MPAD * HID * 2);
  int*      rp    = (int*)alloc((NN + 1) * sizeof(int));
  int*      cur   = (int*)alloc(NN * sizeof(int));
  int*      bsum  = (int*)alloc(NBLK * sizeof(int));
  int*      esrc  = (int*)alloc((size_t)NE * sizeof(int));
  ushort_t* wt    = (ushort_t*)alloc(((size_t)HID * IND + 5 * (size_t)HID * HID) * 2);
  float*    sc1   = (float*)alloc(3 * HID * sizeof(float));
  float*    bi1   = (float*)alloc(3 * HID * sizeof(float));
  float*    sc2   = (float*)alloc(3 * HID * sizeof(float));
  float*    bi2   = (float*)alloc(3 * HID * sizeof(float));
  (void)ws_size; (void)in_sizes; (void)n_in; (void)out_size;

  ushort_t* w1_0t = wt;
  ushort_t* w2_0t = wt + HID * IND;
  ushort_t* w1r0t = wt + HID * IND + 1 * HID * HID;
  ushort_t* w2r0t = wt + HID * IND + 2 * HID * HID;
  ushort_t* w1r1t = wt + HID * IND + 3 * HID * HID;
  ushort_t* w2r1t = wt + HID * IND + 4 * HID * HID;

  // CSR build
  zero_k<<<(NN + 255) / 256, 256, 0, stream>>>(cur, NN);
  hist_k<<<(NE + 255) / 256, 256, 0, stream>>>(dst, cur);
  bsum_k<<<NBLK, 1024, 0, stream>>>(cur, bsum);
  bscan_k<<<1, 64, 0, stream>>>(bsum, rp);
  scan2_k<<<NBLK, 1024, 0, stream>>>(cur, bsum, rp, cur);
  scatter_k<<<(NE + 255) / 256, 256, 0, stream>>>(src, dst, cur, esrc);

  // weight/BN prep
  prepw_k<<<dim3(HID, 6), 256, 0, stream>>>(w1_0, w2_0, w1_r, w2_r, wt);
  prepbn_k<<<3, 256, 0, stream>>>(b1_0, b2_0, g0, be0, m0, v0,
                                  b1_r, b2_r, g_r, be_r, m_r, v_r,
                                  sc1, bi1, sc2, bi2);

  dim3 gg(NTILES_M, 2);
  // layer 0
  agg_f32_k<<<NN / 4, 256, 0, stream>>>(x, rp, esrc, bufA);
  gemm_k<<<gg, 256, 0, stream>>>(bufA, w1_0t, sc1, bi1, bufB, IND, 1, 0);
  gemm_k<<<gg, 256, 0, stream>>>(bufB, w2_0t, sc2, bi2, bufA, HID, 1, 0);
  // layer 1
  agg_bf_k<<<NN / 4, 256, 0, stream>>>(bufA, rp, esrc, bufB);
  gemm_k<<<gg, 256, 0, stream>>>(bufB, w1r0t, sc1 + HID, bi1 + HID, bufA, HID, 1, 0);
  gemm_k<<<gg, 256, 0, stream>>>(bufA, w2r0t, sc2 + HID, bi2 + HID, bufB, HID, 1, 0);
  // layer 2
  agg_bf_k<<<NN / 4, 256, 0, stream>>>(bufB, rp, esrc, bufA);
  gemm_k<<<gg, 256, 0, stream>>>(bufA, w1r1t, sc1 + 2 * HID, bi1 + 2 * HID, bufB, HID, 1, 0);
  gemm_k<<<gg, 256, 0, stream>>>(bufB, w2r1t, sc2 + 2 * HID, bi2 + 2 * HID, d_out, HID, 0, 1);
}